// Round 9
// baseline (250.992 us; speedup 1.0000x reference)
//
#include <hip/hip_runtime.h>
#include <stdint.h>
#include <stddef.h>

#define BB 4
#define NN 4096
#define DD 128

typedef _Float16 f16;
typedef _Float16 f16x8 __attribute__((ext_vector_type(8)));
typedef float f32x4 __attribute__((ext_vector_type(4)));

#define WAITV(N) asm volatile("s_waitcnt vmcnt(" #N ")" ::: "memory")
#define WAITL0() asm volatile("s_waitcnt lgkmcnt(0)" ::: "memory")
#define SCHED0() __builtin_amdgcn_sched_barrier(0)

__device__ __forceinline__ void gl16(const f16* g, f16* l) {
  __builtin_amdgcn_global_load_lds(
      (const __attribute__((address_space(1))) unsigned int*)g,
      (__attribute__((address_space(3))) unsigned int*)l,
      16, 0, 0);
}
__device__ __forceinline__ void gl16f(const float* g, float* l) {
  __builtin_amdgcn_global_load_lds(
      (const __attribute__((address_space(1))) unsigned int*)g,
      (__attribute__((address_space(3))) unsigned int*)l,
      16, 0, 0);
}

__device__ __forceinline__ float fast_sqrt(float x) {
  float r;
  asm("v_sqrt_f32 %0, %1" : "=v"(r) : "v"(x));
  return r;
}

// ---- prep: f16 hi/lo split, numpy-exact row norms, input copies ----------
__global__ __launch_bounds__(256) void prep_kernel(
    const float* __restrict__ x1, const float* __restrict__ x2,
    f16* __restrict__ x1h, f16* __restrict__ x1l,
    f16* __restrict__ x2h, f16* __restrict__ x2l,
    float* __restrict__ sq1, float* __restrict__ sq2,
    float* __restrict__ out)
{
  int gtid = blockIdx.x * blockDim.x + threadIdx.x;
  int gwave = gtid >> 6;
  int lane = gtid & 63;
  int sub = lane >> 3;
  int j = lane & 7;
  int row = gwave * 8 + sub;
  const float* src; f16* dh; f16* dl; float* sq; float* cpy; int r;
  if (row < BB * NN) {
    r = row; src = x1; dh = x1h; dl = x1l; sq = sq1; cpy = out;
  } else {
    r = row - BB * NN; src = x2; dh = x2h; dl = x2l; sq = sq2;
    cpy = out + (size_t)BB * NN * DD;
  }
  const float* p = src + (size_t)r * DD;
  float acc = 0.0f;
  #pragma unroll
  for (int i = 0; i < DD / 8; ++i) {
    int c = j + i * 8;
    float v = p[c];
    float s = v * v;
    acc = (i == 0) ? s : (acc + s);
    f16 h = (f16)v;
    f16 l = (f16)(v - (float)h);
    dh[(size_t)r * DD + c] = h;
    dl[(size_t)r * DD + c] = l;
    cpy[(size_t)r * DD + c] = v;
  }
  acc = acc + __shfl_xor(acc, 1);
  acc = acc + __shfl_xor(acc, 2);
  acc = acc + __shfl_xor(acc, 4);
  if (j == 0) sq[r] = acc;
}

// ---- main: PERSISTENT blocks (512 = 2/CU), each does 8 tiles of 128x128.
//      Counted-vmcnt pipeline: corr stores of tile t stay in flight under
//      GEMM of tile t+1 (raw s_barrier + s_waitcnt vmcnt(N), no vmcnt(0)
//      drain at iter boundaries). Plain stores, smooth per-CU trickle. ----
__global__ __launch_bounds__(512, 4) void cdist_kernel(
    const f16* __restrict__ x1h, const f16* __restrict__ x1l,
    const f16* __restrict__ x2h, const f16* __restrict__ x2l,
    const float* __restrict__ sq1, const float* __restrict__ sq2,
    float* __restrict__ corr,
    float* __restrict__ p21v, int* __restrict__ p21i,
    float* __restrict__ p12v, int* __restrict__ p12i)
{
  __shared__ f16 Ah[2][128 * 32];
  __shared__ f16 Al[2][128 * 32];
  __shared__ f16 Bh[2][128 * 32];
  __shared__ f16 Bl[2][128 * 32];
  __shared__ float s1s[128];
  __shared__ float s2s[128];

  const int blk = blockIdx.x;
  const int xcd = blk & 7;     // hw round-robin XCD assumption (perf-only)
  const int slot = blk >> 3;   // 0..63

  const int t = threadIdx.x;
  const int wid = t >> 6;
  const int lane = t & 63;
  const int wm = wid & 1;    // n1 64-half
  const int wn = wid >> 1;   // n2 32-quarter
  const int lr = lane & 15;
  const int lg = lane >> 4;

  const int rowc = t >> 2;
  const int kc8 = ((t & 3) ^ (rowc & 3) ^ ((rowc >> 2) & 3)) * 8;
  const int loff = (wid * 64) * 8;   // wave-uniform LDS base (f16 elems)
  const int lgx8 = (lg ^ (lr & 3) ^ ((lr >> 2) & 3)) * 8;
  const int offA0 = (wm * 64 + lr) * 32 + lgx8;
  const int offB0 = (wn * 32 + lr) * 32 + lgx8;

  // tile ti (0..7): batch = ti>>1; lin = xcd*128 + (ti&1)*64 + slot
#define GEOM(ti, b_, bn1_, bn2_) \
    int lin_##ti = xcd * 128 + ((ti) & 1) * 64 + slot; \
    b_ = (ti) >> 1; bn1_ = (lin_##ti & 31) * 128; bn2_ = (lin_##ti >> 5) * 128;

  // boundary issue for a tile: norms(2) + stage k0=0 -> buf0 (4) + k0=32 -> buf1 (4)
#define BOUNDARY(b_, bn1_, bn2_) do { \
    if (lane < 32) { \
      gl16f(sq1 + (size_t)(b_) * NN + (bn1_) + lane * 4, s1s); \
      gl16f(sq2 + (size_t)(b_) * NN + (bn2_) + lane * 4, s2s); \
    } \
    SCHED0(); \
    const size_t base_ = (size_t)(b_) * NN * DD; \
    const int ao_ = (bn1_ + rowc) * DD + kc8; \
    const int bo_ = (bn2_ + rowc) * DD + kc8; \
    gl16(x1h + base_ + ao_, &Ah[0][loff]); \
    gl16(x1l + base_ + ao_, &Al[0][loff]); \
    gl16(x2h + base_ + bo_, &Bh[0][loff]); \
    gl16(x2l + base_ + bo_, &Bl[0][loff]); \
    SCHED0(); \
    gl16(x1h + base_ + ao_ + 32, &Ah[1][loff]); \
    gl16(x1l + base_ + ao_ + 32, &Al[1][loff]); \
    gl16(x2h + base_ + bo_ + 32, &Bh[1][loff]); \
    gl16(x2l + base_ + bo_ + 32, &Bl[1][loff]); \
    SCHED0(); } while (0)

  {
    int b0, bn10, bn20;
    GEOM(0, b0, bn10, bn20);
    BOUNDARY(b0, bn10, bn20);
  }

  for (int ti = 0; ti < 8; ++ti) {
    int b, bn1, bn2;
    GEOM(ti, b, bn1, bn2);
    const size_t base = (size_t)b * NN * DD;
    const int ao = (bn1 + rowc) * DD + kc8;
    const int bo = (bn2 + rowc) * DD + kc8;

    f32x4 acc[4][2];
    #pragma unroll
    for (int m = 0; m < 4; ++m)
      #pragma unroll
      for (int n = 0; n < 2; ++n)
        #pragma unroll
        for (int q = 0; q < 4; ++q) acc[m][n][q] = 0.0f;

    #pragma unroll
    for (int k = 0; k < 4; ++k) {
      // own lgkm drained before barrier (LDS reads retired -> overwrite safe)
      WAITL0(); SCHED0();
      // counted vmcnt: wait own stage-k; keep younger stores in flight
      if (ti == 0) { if (k == 0) WAITV(4); else WAITV(0); }
      else { if (k == 0) WAITV(12); else if (k == 1) WAITV(8); else WAITV(0); }
      __builtin_amdgcn_s_barrier();
      SCHED0();
      if (k == 1) {   // stage k=2 -> buf0 (iter0 reads done block-wide)
        gl16(x1h + base + ao + 64, &Ah[0][loff]);
        gl16(x1l + base + ao + 64, &Al[0][loff]);
        gl16(x2h + base + bo + 64, &Bh[0][loff]);
        gl16(x2l + base + bo + 64, &Bl[0][loff]);
      }
      if (k == 2) {   // stage k=3 -> buf1
        gl16(x1h + base + ao + 96, &Ah[1][loff]);
        gl16(x1l + base + ao + 96, &Al[1][loff]);
        gl16(x2h + base + bo + 96, &Bh[1][loff]);
        gl16(x2l + base + bo + 96, &Bl[1][loff]);
      }
      SCHED0();
      const int bf = k & 1;
      f16x8 fah[4], fal[4], fbh[2], fbl[2];
      #pragma unroll
      for (int m = 0; m < 4; ++m) {
        fah[m] = *(const f16x8*)&Ah[bf][offA0 + m * 512];
        fal[m] = *(const f16x8*)&Al[bf][offA0 + m * 512];
      }
      #pragma unroll
      for (int n = 0; n < 2; ++n) {
        fbh[n] = *(const f16x8*)&Bh[bf][offB0 + n * 512];
        fbl[n] = *(const f16x8*)&Bl[bf][offB0 + n * 512];
      }
      #pragma unroll
      for (int m = 0; m < 4; ++m)
        #pragma unroll
        for (int n = 0; n < 2; ++n) {
          acc[m][n] = __builtin_amdgcn_mfma_f32_16x16x32_f16(fah[m], fbh[n], acc[m][n], 0, 0, 0);
          acc[m][n] = __builtin_amdgcn_mfma_f32_16x16x32_f16(fah[m], fbl[n], acc[m][n], 0, 0, 0);
          acc[m][n] = __builtin_amdgcn_mfma_f32_16x16x32_f16(fal[m], fbh[n], acc[m][n], 0, 0, 0);
        }
    }

    // ---- epilogue: dist (sq-space argmin), partial stores PRE-barrier ----
    float s2r[2];
    #pragma unroll
    for (int n = 0; n < 2; ++n) s2r[n] = s2s[wn * 32 + n * 16 + lr];
    float s1r[4][4];
    #pragma unroll
    for (int m = 0; m < 4; ++m)
      #pragma unroll
      for (int q = 0; q < 4; ++q) s1r[m][q] = s1s[wm * 64 + m * 16 + lg * 4 + q];

    f32x4 dv[4][2];
    float v21[2]; int i21[2];
    #pragma unroll
    for (int n = 0; n < 2; ++n) { v21[n] = 3.4e38f; i21[n] = 0; }

    const int sbx = bn1 >> 7;
    const int sby = bn2 >> 7;
    #pragma unroll
    for (int m = 0; m < 4; ++m) {
      const int n1b = wm * 64 + m * 16 + lg * 4;
      float v12[4]; int i12[4];
      #pragma unroll
      for (int q = 0; q < 4; ++q) { v12[q] = 3.4e38f; i12[q] = 0; }
      #pragma unroll
      for (int n = 0; n < 2; ++n) {
        float sqc[4];
        #pragma unroll
        for (int q = 0; q < 4; ++q) {
          const float sv = fmaxf(fmaf(-2.0f, acc[m][n][q], s1r[m][q] + s2r[n]), 0.0f);
          sqc[q] = sv;
          dv[m][n][q] = fast_sqrt(sv);
        }
        const int n2l = wn * 32 + n * 16 + lr;
        #pragma unroll
        for (int q = 0; q < 4; ++q) {
          // n1 ascends with (m,q); n2 ascends with n: strict < = first-index
          if (sqc[q] < v21[n]) { v21[n] = sqc[q]; i21[n] = bn1 + n1b + q; }
          if (sqc[q] < v12[q]) { v12[q] = sqc[q]; i12[q] = bn2 + n2l; }
        }
      }
      #pragma unroll
      for (int q = 0; q < 4; ++q) {
        float v = v12[q]; int idx = i12[q];
        #pragma unroll
        for (int mask = 1; mask < 16; mask <<= 1) {
          float ov = __shfl_xor(v, mask);
          int oi = __shfl_xor(idx, mask);
          if (ov < v || (ov == v && oi < idx)) { v = ov; idx = oi; }
        }
        if (lr == 0) {
          const int colg = bn1 + n1b + q;
          const size_t o = ((size_t)b * NN + colg) * 128 + (sby * 4 + wn);
          p12v[o] = v; p12i[o] = idx;
        }
      }
    }
    #pragma unroll
    for (int n = 0; n < 2; ++n) {
      float v = v21[n]; int idx = i21[n];
      #pragma unroll
      for (int mask = 16; mask < 64; mask <<= 1) {
        float ov = __shfl_xor(v, mask);
        int oi = __shfl_xor(idx, mask);
        if (ov < v || (ov == v && oi < idx)) { v = ov; idx = oi; }
      }
      if (lg == 0) {
        const int rowg = bn2 + wn * 32 + n * 16 + lr;
        const size_t o = ((size_t)b * NN + rowg) * 64 + (sbx * 2 + wm);
        p21v[o] = v; p21i[o] = idx;
      }
    }

    // ---- boundary: barrier, next-tile staging, THEN corr stores ----
    WAITL0(); SCHED0();
    __builtin_amdgcn_s_barrier();
    SCHED0();
    if (ti < 7) {
      int bN, bn1N, bn2N;
      if (ti == 0) { GEOM(1, bN, bn1N, bn2N); BOUNDARY(bN, bn1N, bn2N); }
      else if (ti == 1) { GEOM(2, bN, bn1N, bn2N); BOUNDARY(bN, bn1N, bn2N); }
      else if (ti == 2) { GEOM(3, bN, bn1N, bn2N); BOUNDARY(bN, bn1N, bn2N); }
      else if (ti == 3) { GEOM(4, bN, bn1N, bn2N); BOUNDARY(bN, bn1N, bn2N); }
      else if (ti == 4) { GEOM(5, bN, bn1N, bn2N); BOUNDARY(bN, bn1N, bn2N); }
      else if (ti == 5) { GEOM(6, bN, bn1N, bn2N); BOUNDARY(bN, bn1N, bn2N); }
      else { GEOM(7, bN, bn1N, bn2N); BOUNDARY(bN, bn1N, bn2N); }
    }
    SCHED0();
    // 8 plain corr stores (stay in flight through next tile's iters 0-1)
    float* cbp = corr + (size_t)b * NN * NN;
    #pragma unroll
    for (int m = 0; m < 4; ++m) {
      const int n1b = wm * 64 + m * 16 + lg * 4;
      #pragma unroll
      for (int n = 0; n < 2; ++n) {
        const int n2g = bn2 + wn * 32 + n * 16 + lr;
        *(f32x4*)(cbp + (size_t)n2g * NN + (bn1 + n1b)) = dv[m][n];
      }
    }
    SCHED0();
  }
#undef BOUNDARY
#undef GEOM
}

// ---- final argmin: p21 rows have 64 partials, p12 rows have 128 ---------
__global__ __launch_bounds__(256) void argmin_reduce_kernel(
    const float* __restrict__ p21v, const int* __restrict__ p21i,
    const float* __restrict__ p12v, const int* __restrict__ p12i,
    float* __restrict__ out_i12, float* __restrict__ out_i21)
{
  int gtid = blockIdx.x * blockDim.x + threadIdx.x;
  int gwave = gtid >> 6;
  int lane = gtid & 63;
  float v; int idx; float* dst; int r;
  if (gwave < BB * NN) {
    r = gwave;
    v = p21v[(size_t)r * 64 + lane];
    idx = p21i[(size_t)r * 64 + lane];
    dst = out_i21;
  } else {
    r = gwave - BB * NN;
    v = p12v[(size_t)r * 128 + lane];
    idx = p12i[(size_t)r * 128 + lane];
    float v2 = p12v[(size_t)r * 128 + 64 + lane];
    int i2 = p12i[(size_t)r * 128 + 64 + lane];
    if (v2 < v || (v2 == v && i2 < idx)) { v = v2; idx = i2; }
    dst = out_i12;
  }
  #pragma unroll
  for (int mask = 1; mask < 64; mask <<= 1) {
    float ov = __shfl_xor(v, mask);
    int oi = __shfl_xor(idx, mask);
    if (ov < v || (ov == v && oi < idx)) { v = ov; idx = oi; }
  }
  if (lane == 0) dst[r] = (float)idx;
}

extern "C" void kernel_launch(void* const* d_in, const int* in_sizes, int n_in,
                              void* d_out, int out_size, void* d_ws, size_t ws_size,
                              hipStream_t stream) {
  (void)in_sizes; (void)n_in; (void)out_size; (void)ws_size;
  const float* x1 = (const float*)d_in[0];
  const float* x2 = (const float*)d_in[1];
  float* out = (float*)d_out;
  char* ws = (char*)d_ws;
  const size_t nd = (size_t)BB * NN * DD;
  const size_t bn = (size_t)BB * NN;

  f16* x1h = (f16*)(ws + 0 * nd * 2);
  f16* x1l = (f16*)(ws + 1 * nd * 2);
  f16* x2h = (f16*)(ws + 2 * nd * 2);
  f16* x2l = (f16*)(ws + 3 * nd * 2);
  float* sq1 = (float*)(ws + 4 * nd * 2);
  float* sq2 = (float*)(ws + 4 * nd * 2 + bn * 4);
  char* pbase = ws + 4 * nd * 2 + 2 * bn * 4;
  float* p21v = (float*)(pbase);
  int*   p21i = (int*)  (pbase + 1 * bn * 64 * 4);
  float* p12v = (float*)(pbase + 2 * bn * 64 * 4);
  int*   p12i = (int*)  (pbase + 2 * bn * 64 * 4 + bn * 128 * 4);

  hipLaunchKernelGGL(prep_kernel, dim3(1024), dim3(256), 0, stream,
                     x1, x2, x1h, x1l, x2h, x2l, sq1, sq2, out);

  float* corr = out + 2 * nd;
  // persistent: 512 blocks (2/CU), 8 tiles each
  hipLaunchKernelGGL(cdist_kernel, dim3(512), dim3(512), 0, stream,
                     x1h, x1l, x2h, x2l, sq1, sq2, corr, p21v, p21i, p12v, p12i);

  float* out_i12 = out + 2 * nd + bn * (size_t)NN;
  float* out_i21 = out_i12 + bn;
  hipLaunchKernelGGL(argmin_reduce_kernel, dim3(8192), dim3(256), 0, stream,
                     p21v, p21i, p12v, p12i, out_i12, out_i21);
}

// Round 10
// 158.731 us; speedup vs baseline: 1.5812x; 1.5812x over previous
//
#include <hip/hip_runtime.h>
#include <stdint.h>
#include <stddef.h>

#define BB 4
#define NN 4096
#define DD 128

typedef _Float16 f16;
typedef _Float16 f16x8 __attribute__((ext_vector_type(8)));
typedef float f32x4 __attribute__((ext_vector_type(4)));
typedef float f32x2 __attribute__((ext_vector_type(2)));

__device__ __forceinline__ void gl16(const f16* g, f16* l) {
  __builtin_amdgcn_global_load_lds(
      (const __attribute__((address_space(1))) unsigned int*)g,
      (__attribute__((address_space(3))) unsigned int*)l,
      16, 0, 0);
}

__device__ __forceinline__ float fast_sqrt(float x) {
  float r;
  asm("v_sqrt_f32 %0, %1" : "=v"(r) : "v"(x));
  return r;
}

// ---- prep: f16 hi/lo split, numpy-exact row norms, input copies ----------
__global__ __launch_bounds__(256) void prep_kernel(
    const float* __restrict__ x1, const float* __restrict__ x2,
    f16* __restrict__ x1h, f16* __restrict__ x1l,
    f16* __restrict__ x2h, f16* __restrict__ x2l,
    float* __restrict__ sq1, float* __restrict__ sq2,
    float* __restrict__ out)
{
  int gtid = blockIdx.x * blockDim.x + threadIdx.x;
  int gwave = gtid >> 6;
  int lane = gtid & 63;
  int sub = lane >> 3;
  int j = lane & 7;
  int row = gwave * 8 + sub;
  const float* src; f16* dh; f16* dl; float* sq; float* cpy; int r;
  if (row < BB * NN) {
    r = row; src = x1; dh = x1h; dl = x1l; sq = sq1; cpy = out;
  } else {
    r = row - BB * NN; src = x2; dh = x2h; dl = x2l; sq = sq2;
    cpy = out + (size_t)BB * NN * DD;
  }
  const float* p = src + (size_t)r * DD;
  float acc = 0.0f;
  #pragma unroll
  for (int i = 0; i < DD / 8; ++i) {
    int c = j + i * 8;
    float v = p[c];
    float s = v * v;
    acc = (i == 0) ? s : (acc + s);
    f16 h = (f16)v;
    f16 l = (f16)(v - (float)h);
    dh[(size_t)r * DD + c] = h;
    dl[(size_t)r * DD + c] = l;
    cpy[(size_t)r * DD + c] = v;
  }
  acc = acc + __shfl_xor(acc, 1);
  acc = acc + __shfl_xor(acc, 2);
  acc = acc + __shfl_xor(acc, 4);
  if (j == 0) sq[r] = acc;
}

// ---- main: 256(n1)x128(n2) tile, 8 waves (4x2, 64x64 each), BK=32,
//      split-f16, single-buffer 2-barrier loop (R3 skeleton), 3 blocks/CU,
//      NT stores, swizzled LDS, paired f32x2 partials, XCD swizzle --------
__global__ __launch_bounds__(512, 3) void cdist_kernel(
    const f16* __restrict__ x1h, const f16* __restrict__ x1l,
    const f16* __restrict__ x2h, const f16* __restrict__ x2l,
    const float* __restrict__ sq1, const float* __restrict__ sq2,
    float* __restrict__ corr,
    f32x2* __restrict__ p21, f32x2* __restrict__ p12)
{
  __shared__ f16 Ah[256 * 32];
  __shared__ f16 Al[256 * 32];
  __shared__ f16 Bh[128 * 32];
  __shared__ f16 Bl[128 * 32];
  __shared__ float s1s[256];
  __shared__ float s2s[128];

  const int b = blockIdx.z;
  // bijective XCD swizzle over 512 xy tiles (512 % 8 == 0)
  int lin = blockIdx.y * 16 + blockIdx.x;
  lin = (lin & 7) * 64 + (lin >> 3);
  const int sbx = lin & 15;    // n1 tile (256 wide)
  const int sby = lin >> 4;    // n2 tile (128 tall)
  const int bn1 = sbx * 256;
  const int bn2 = sby * 128;

  const int t = threadIdx.x;
  const int wa = t >> 6;
  const int lane = t & 63;
  const int w1 = wa & 3;     // n1 64-quadrant
  const int w2 = wa >> 2;    // n2 64-half
  const int lr = lane & 15;
  const int lg = lane >> 4;

  const f16* gAh = x1h + (size_t)b * NN * DD;
  const f16* gAl = x1l + (size_t)b * NN * DD;
  const f16* gBh = x2h + (size_t)b * NN * DD;
  const f16* gBl = x2l + (size_t)b * NN * DD;

  if (t < 256) s1s[t] = sq1[(size_t)b * NN + bn1 + t];
  else if (t < 384) s2s[t - 256] = sq2[(size_t)b * NN + bn2 + (t - 256)];

  // staging geometry (swizzled global source, linear LDS dest, rule #21)
  // A: 2 rounds of 512x16B per array; B: 1 round.
  int aoff_[2];
  #pragma unroll
  for (int r = 0; r < 2; ++r) {
    const int c = r * 512 + t;
    const int rowc = c >> 2;
    const int kc = (c & 3) ^ (rowc & 3) ^ ((rowc >> 2) & 3);
    aoff_[r] = (bn1 + rowc) * DD + kc * 8;
  }
  const int browc = t >> 2;
  const int bkc = (t & 3) ^ (browc & 3) ^ ((browc >> 2) & 3);
  const int boff = (bn2 + browc) * DD + bkc * 8;
  const int lofA0 = (wa * 64) * 8;          // round-0 wave base (elems)
  const int lofA1 = (512 + wa * 64) * 8;    // round-1 wave base
#define STAGE(k0) do { \
    gl16(gAh + aoff_[0] + (k0), &Ah[lofA0]); \
    gl16(gAh + aoff_[1] + (k0), &Ah[lofA1]); \
    gl16(gAl + aoff_[0] + (k0), &Al[lofA0]); \
    gl16(gAl + aoff_[1] + (k0), &Al[lofA1]); \
    gl16(gBh + boff + (k0), &Bh[lofA0]); \
    gl16(gBl + boff + (k0), &Bl[lofA0]); } while (0)

  f32x4 acc[4][4];
  #pragma unroll
  for (int m = 0; m < 4; ++m)
    #pragma unroll
    for (int n = 0; n < 4; ++n)
      #pragma unroll
      for (int q = 0; q < 4; ++q) acc[m][n][q] = 0.0f;

  STAGE(0);

  // swizzled read offset (row & 15 == lr for all fragment rows)
  const int lgx8 = (lg ^ (lr & 3) ^ ((lr >> 2) & 3)) * 8;
  const int offA0 = (w1 * 64 + lr) * 32 + lgx8;
  const int offB0 = (w2 * 64 + lr) * 32 + lgx8;

  for (int it = 0; it < 4; ++it) {
    __syncthreads();   // vmcnt drain == stage(it) landed
    f16x8 fah[4], fal[4], fbh[4], fbl[4];
    #pragma unroll
    for (int m = 0; m < 4; ++m) {
      fah[m] = *(const f16x8*)&Ah[offA0 + m * 512];
      fal[m] = *(const f16x8*)&Al[offA0 + m * 512];
    }
    #pragma unroll
    for (int n = 0; n < 4; ++n) {
      fbh[n] = *(const f16x8*)&Bh[offB0 + n * 512];
      fbl[n] = *(const f16x8*)&Bl[offB0 + n * 512];
    }
    __syncthreads();   // reads landed -> buffer free
    if (it < 3) STAGE((it + 1) * 32);   // flies under MFMAs
    #pragma unroll
    for (int m = 0; m < 4; ++m)
      #pragma unroll
      for (int n = 0; n < 4; ++n) {
        acc[m][n] = __builtin_amdgcn_mfma_f32_16x16x32_f16(fah[m], fbh[n], acc[m][n], 0, 0, 0);
        acc[m][n] = __builtin_amdgcn_mfma_f32_16x16x32_f16(fah[m], fbl[n], acc[m][n], 0, 0, 0);
        acc[m][n] = __builtin_amdgcn_mfma_f32_16x16x32_f16(fal[m], fbh[n], acc[m][n], 0, 0, 0);
      }
  }
#undef STAGE

  // ---- epilogue ----
  // corr-col n1 = bn1 + w1*64 + m*16 + lg*4 + q
  // corr-row n2 = bn2 + w2*64 + n*16 + lr
  float s2r[4];
  #pragma unroll
  for (int n = 0; n < 4; ++n) s2r[n] = s2s[w2 * 64 + n * 16 + lr];
  float s1r[4][4];
  #pragma unroll
  for (int m = 0; m < 4; ++m)
    #pragma unroll
    for (int q = 0; q < 4; ++q) s1r[m][q] = s1s[w1 * 64 + m * 16 + lg * 4 + q];

  float v21[4]; int i21[4];   // per n-row: min over this thread's 16 cols
  #pragma unroll
  for (int n = 0; n < 4; ++n) { v21[n] = 3.4e38f; i21[n] = 0; }

  float* cbp = corr + (size_t)b * NN * NN;
  #pragma unroll
  for (int m = 0; m < 4; ++m) {
    const int n1b = bn1 + w1 * 64 + m * 16 + lg * 4;
    float v12[4]; int i12[4];   // per q-col: min over this thread's 4 rows
    #pragma unroll
    for (int q = 0; q < 4; ++q) { v12[q] = 3.4e38f; i12[q] = 0; }
    #pragma unroll
    for (int n = 0; n < 4; ++n) {
      const int n2g = bn2 + w2 * 64 + n * 16 + lr;
      f32x4 dv;
      float sqc[4];
      #pragma unroll
      for (int q = 0; q < 4; ++q) {
        const float sv = fmaxf(fmaf(-2.0f, acc[m][n][q], s1r[m][q] + s2r[n]), 0.0f);
        sqc[q] = sv;
        dv[q] = fast_sqrt(sv);
      }
      __builtin_nontemporal_store(dv, (f32x4*)(cbp + (size_t)n2g * NN + n1b));
      #pragma unroll
      for (int q = 0; q < 4; ++q) {
        // n1 ascends with (m,q); n2 ascends with n: strict < = first-index
        if (sqc[q] < v21[n]) { v21[n] = sqc[q]; i21[n] = n1b + q; }
        if (sqc[q] < v12[q]) { v12[q] = sqc[q]; i12[q] = n2g; }
      }
    }
    // reduce v12 over the 16 lr-lanes (rows); write per-col block partial
    #pragma unroll
    for (int q = 0; q < 4; ++q) {
      float v = v12[q]; int idx = i12[q];
      #pragma unroll
      for (int mask = 1; mask < 16; mask <<= 1) {
        float ov = __shfl_xor(v, mask);
        int oi = __shfl_xor(idx, mask);
        if (ov < v || (ov == v && oi < idx)) { v = ov; idx = oi; }
      }
      if (lr == 0) {
        const size_t o = (size_t)((b * 32 + sby) * 2 + w2) * NN + (n1b + q);
        p12[o] = f32x2{v, __int_as_float(idx)};
      }
    }
  }
  // reduce v21 over the 4 lg-lanes (cols); write per-row block partial
  #pragma unroll
  for (int n = 0; n < 4; ++n) {
    float v = v21[n]; int idx = i21[n];
    #pragma unroll
    for (int mask = 16; mask < 64; mask <<= 1) {
      float ov = __shfl_xor(v, mask);
      int oi = __shfl_xor(idx, mask);
      if (ov < v || (ov == v && oi < idx)) { v = ov; idx = oi; }
    }
    if (lg == 0) {
      const int rowg = bn2 + w2 * 64 + n * 16 + lr;
      const size_t o = (size_t)((b * 16 + sbx) * 4 + w1) * NN + rowg;
      p21[o] = f32x2{v, __int_as_float(idx)};
    }
  }
}

// ---- final argmin: 64 f32x2 partials per output, one wave each ----------
__global__ __launch_bounds__(256) void argmin_reduce_kernel(
    const f32x2* __restrict__ p21, const f32x2* __restrict__ p12,
    float* __restrict__ out_i12, float* __restrict__ out_i21)
{
  int gtid = blockIdx.x * blockDim.x + threadIdx.x;
  int gwave = gtid >> 6;
  int lane = gtid & 63;
  f32x2 e; float* dst; int r;
  if (gwave < BB * NN) {
    r = gwave;
    const int b = r >> 12, row = r & (NN - 1);
    e = p21[(size_t)((b * 16 + (lane >> 2)) * 4 + (lane & 3)) * NN + row];
    dst = out_i21;
  } else {
    r = gwave - BB * NN;
    const int b = r >> 12, col = r & (NN - 1);
    e = p12[(size_t)((b * 32 + (lane >> 1)) * 2 + (lane & 1)) * NN + col];
    dst = out_i12;
  }
  float v = e[0]; int idx = __float_as_int(e[1]);
  #pragma unroll
  for (int mask = 1; mask < 64; mask <<= 1) {
    float ov = __shfl_xor(v, mask);
    int oi = __shfl_xor(idx, mask);
    if (ov < v || (ov == v && oi < idx)) { v = ov; idx = oi; }
  }
  if (lane == 0) dst[r] = (float)idx;
}

extern "C" void kernel_launch(void* const* d_in, const int* in_sizes, int n_in,
                              void* d_out, int out_size, void* d_ws, size_t ws_size,
                              hipStream_t stream) {
  (void)in_sizes; (void)n_in; (void)out_size; (void)ws_size;
  const float* x1 = (const float*)d_in[0];
  const float* x2 = (const float*)d_in[1];
  float* out = (float*)d_out;
  char* ws = (char*)d_ws;
  const size_t nd = (size_t)BB * NN * DD;     // elems per input
  const size_t bn = (size_t)BB * NN;

  f16* x1h = (f16*)(ws + 0 * nd * 2);
  f16* x1l = (f16*)(ws + 1 * nd * 2);
  f16* x2h = (f16*)(ws + 2 * nd * 2);
  f16* x2l = (f16*)(ws + 3 * nd * 2);
  float* sq1 = (float*)(ws + 4 * nd * 2);
  float* sq2 = (float*)(ws + 4 * nd * 2 + bn * 4);
  f32x2* p21 = (f32x2*)(ws + 4 * nd * 2 + 2 * bn * 4);          // 8 MB
  f32x2* p12 = (f32x2*)(ws + 4 * nd * 2 + 2 * bn * 4 + bn * 64 * 8);  // 8 MB

  hipLaunchKernelGGL(prep_kernel, dim3(1024), dim3(256), 0, stream,
                     x1, x2, x1h, x1l, x2h, x2l, sq1, sq2, out);

  float* corr = out + 2 * nd;
  // grid: 16 n1-tiles x 32 n2-tiles x 4 batches, 512-thread blocks
  hipLaunchKernelGGL(cdist_kernel, dim3(16, 32, 4), dim3(512), 0, stream,
                     x1h, x1l, x2h, x2l, sq1, sq2, corr, p21, p12);

  float* out_i12 = out + 2 * nd + bn * (size_t)NN;
  float* out_i21 = out_i12 + bn;
  hipLaunchKernelGGL(argmin_reduce_kernel, dim3(8192), dim3(256), 0, stream,
                     p21, p12, out_i12, out_i21);
}